// Round 20
// baseline (218.622 us; speedup 1.0000x reference)
//
#include <hip/hip_runtime.h>
#include <hip/hip_bf16.h>

typedef __attribute__((ext_vector_type(8))) short bf16x8;
typedef __attribute__((ext_vector_type(4))) float f32x4;

#define NCOLP 384
#define STEP_SHORTS 12288  // 384 cols * 32 k
#define STEP_BYTES 24576
#define NSTEP 32
#define BROWS 65536
#define SLOT 65536  // per-buffer: A 16KB + B 48KB
#define BOFF 16384

static __device__ __forceinline__ unsigned int bf16rne(float f) {
  unsigned int u = __float_as_uint(f);
  return (u + 0x7FFFu + ((u >> 16) & 1u)) >> 16;
}
static __device__ __forceinline__ unsigned int pack2(float a, float b) {
  return bf16rne(a) | (bf16rne(b) << 16);
}
static __device__ __forceinline__ void gload16(const void* g, void* l) {
  __builtin_amdgcn_global_load_lds(
      (const __attribute__((address_space(1))) unsigned int*)g,
      (__attribute__((address_space(3))) unsigned int*)l, 16, 0, 0);
}

// Wpack layout: [step][col(384)][k%32 linear] (bf16), 24576 B/step.
// Lane (arow,ablk) reads col*64B + ablk*16B -> k = ablk*8+i (matches A).
// Column map: [0,100) task0 (e*10+h), [100,200) task1, [200,300) shared,
// [300,340) gates (t*20+g), [340,384) zero pad.
__global__ void ple_prep(const float* __restrict__ Ws, const float* __restrict__ bs,
                         const float* __restrict__ Wt, const float* __restrict__ bt,
                         const float* __restrict__ Wg, const float* __restrict__ bg,
                         unsigned short* __restrict__ Wpack, float* __restrict__ bias) {
  const int n = blockIdx.x;  // 0..383
  const int tid = threadIdx.x;
  const float* src = nullptr;
  int stride = 0;
  float bval = 0.f;
  if (n < 200) {
    int t = n / 100, m = n % 100, e = m / 10, h = m % 10;
    src = Wt + (size_t)(t * 10 + e) * 10240 + h;
    stride = 10;
    bval = bt[(t * 10 + e) * 10 + h];
  } else if (n < 300) {
    int m = n - 200, e = m / 10, h = m % 10;
    src = Ws + (size_t)e * 10240 + h;
    stride = 10;
    bval = bs[e * 10 + h];
  } else if (n < 340) {
    int m = n - 300, t = m / 20, g = m % 20;
    src = Wg + (size_t)t * 20480 + g;
    stride = 20;
    bval = bg[t * 20 + g];
  }
  for (int j = 0; j < 4; j++) {
    int k = tid + j * 256;
    float v = src ? src[(size_t)k * stride] : 0.f;
    Wpack[(size_t)(k >> 5) * STEP_SHORTS + n * 32 + (k & 31)] =
        (unsigned short)bf16rne(v);
  }
  if (tid == 0 && n < 352) bias[n] = bval;
}

// Main: 512 threads = 8 waves, 128 rows/block, 512 blocks, 1 block/CU.
// Double-buffered 16th-of-K tiles (2 K-steps each): stage {A via reg
// (3-bank lead, fp32->bf16 cvt) + B via global_load_lds from L2 (shared by
// all 8 waves -> B-L2 traffic halved vs M=64 register-B)} into buf p^1
// while computing buf p; counted vmcnt(4)+s_barrier per iter keeps the
// next A-loads in flight. Each wave: all 128 rows (8 mf) x 48 cols (3 nt).
__global__ __launch_bounds__(512, 2) void ple_main(
    const float* __restrict__ x, const unsigned short* __restrict__ Wpack,
    const float* __restrict__ bias, const float* __restrict__ Wc,
    const float* __restrict__ bc, const float* __restrict__ Wv,
    const float* __restrict__ bv, float* __restrict__ out) {
  __shared__ __align__(16) char smem[131072];  // 2 x (A 16KB + B 48KB)
  float* z = (float*)smem;                     // epilogue z[16][357]

  const int tid = threadIdx.x;
  const int l = tid & 63, w = tid >> 6;  // wave w -> cols [w*48, w*48+48)
  const int arow = l & 15, ablk = l >> 4;
  const int rowbase = blockIdx.x * 128;

  const f32x4 fzero = {0.f, 0.f, 0.f, 0.f};
  f32x4 acc[8][3];
#pragma unroll
  for (int i = 0; i < 8; ++i)
#pragma unroll
    for (int j = 0; j < 3; ++j) acc[i][j] = fzero;

  // A-fragment read offsets (seg' = (ST*4+ablk)^(arow&7), 16B segs)
  const int a7 = arow & 7;
  const int sgp0 = (ablk ^ a7) * 16;
  const int sgp1 = ((4 + ablk) ^ a7) * 16;
  // B-fragment read offset within a step's B region
  const int brd = (w * 48 + arow) * 64 + ablk * 16;

  // A staging: chunk c = tid + j*512 (j=0..3): row = c>>4 = r0+32j,
  // halfseg h = tid&15 (8B bf16); fully-coalesced 16B fp32 loads.
  const int r0 = tid >> 4;
  const int h = tid & 15;
  const char* xc0 = (const char*)x + (size_t)(rowbase + r0) * 4096 + h * 16;
  const int sB = (((h >> 1) ^ (r0 & 7)) * 16) + (h & 1) * 8;

  const char* wsrc = (const char*)Wpack;

  float4 bk0[4], bk1[4], bk2[4];  // A banks, static indexing only

#define A_LOAD(T, BK)                                                          \
  {                                                                            \
    const char* ap = xc0 + (size_t)((T) < 16 ? (T) : 15) * 256;                \
    BK[0] = *(const float4*)(ap);                                              \
    BK[1] = *(const float4*)(ap + 131072);                                     \
    BK[2] = *(const float4*)(ap + 262144);                                     \
    BK[3] = *(const float4*)(ap + 393216);                                     \
  }
#define A_WRITE(P, BK)                                                         \
  {                                                                            \
    _Pragma("unroll") for (int j = 0; j < 4; j++) {                            \
      uint2 u;                                                                 \
      u.x = pack2(BK[j].x, BK[j].y);                                           \
      u.y = pack2(BK[j].z, BK[j].w);                                           \
      *(uint2*)(smem + (P)*SLOT + (r0 + 32 * j) * 128 + sB) = u;               \
    }                                                                          \
  }
#define B_STAGE(T, P)                                                          \
  {                                                                            \
    const char* s0 = wsrc + (size_t)(((T) < 16 ? (T) : 15) * 2) * STEP_BYTES;  \
    const char* s1 = s0 + STEP_BYTES;                                          \
    char* d0 = smem + (P)*SLOT + BOFF;                                         \
    char* d1 = d0 + STEP_BYTES;                                                \
    gload16(s0 + tid * 16, d0 + tid * 16);                                     \
    gload16(s0 + 8192 + tid * 16, d0 + 8192 + tid * 16);                       \
    gload16(s0 + 16384 + tid * 16, d0 + 16384 + tid * 16);                     \
    gload16(s1 + tid * 16, d1 + tid * 16);                                     \
    gload16(s1 + 8192 + tid * 16, d1 + 8192 + tid * 16);                       \
    gload16(s1 + 16384 + tid * 16, d1 + 16384 + tid * 16);                     \
  }
#define CSTEP(P, ST)                                                           \
  {                                                                            \
    const char* ab = smem + (P)*SLOT;                                          \
    const char* bb = ab + BOFF + (ST)*STEP_BYTES + brd;                        \
    const bf16x8 b0 = *(const bf16x8*)(bb);                                    \
    const bf16x8 b1 = *(const bf16x8*)(bb + 1024);                             \
    const bf16x8 b2 = *(const bf16x8*)(bb + 2048);                             \
    const int sg = (ST) ? sgp1 : sgp0;                                         \
    _Pragma("unroll") for (int mf = 0; mf < 8; mf++) {                         \
      const bf16x8 av = *(const bf16x8*)(ab + (mf * 16 + arow) * 128 + sg);    \
      acc[mf][0] = __builtin_amdgcn_mfma_f32_16x16x32_bf16(av, b0, acc[mf][0], \
                                                           0, 0, 0);           \
      acc[mf][1] = __builtin_amdgcn_mfma_f32_16x16x32_bf16(av, b1, acc[mf][1], \
                                                           0, 0, 0);           \
      acc[mf][2] = __builtin_amdgcn_mfma_f32_16x16x32_bf16(av, b2, acc[mf][2], \
                                                           0, 0, 0);           \
    }                                                                          \
  }
#define ITER(I, BW, BL)                                                        \
  {                                                                            \
    B_STAGE((I) + 1, ((I) + 1) & 1);                                           \
    __builtin_amdgcn_sched_barrier(0);                                         \
    A_WRITE(((I) + 1) & 1, BW);                                                \
    __builtin_amdgcn_sched_barrier(0);                                         \
    A_LOAD((I) + 3, BL);                                                       \
    __builtin_amdgcn_sched_barrier(0);                                         \
    CSTEP((I)&1, 0);                                                           \
    CSTEP((I)&1, 1);                                                           \
    __builtin_amdgcn_sched_barrier(0);                                         \
    asm volatile("s_waitcnt vmcnt(4) lgkmcnt(0)" ::: "memory");                \
    __builtin_amdgcn_s_barrier();                                              \
    __builtin_amdgcn_sched_barrier(0);                                         \
  }

  // ---- prologue: B(0)+A(0) -> buf0; A(1),A(2) in flight ----
  B_STAGE(0, 0);
  __builtin_amdgcn_sched_barrier(0);
  A_LOAD(0, bk0);
  __builtin_amdgcn_sched_barrier(0);
  A_WRITE(0, bk0);  // compiler waits A(0) (drains B(0) too - prologue only)
  A_LOAD(1, bk1);
  A_LOAD(2, bk2);
  __builtin_amdgcn_sched_barrier(0);
  asm volatile("s_waitcnt lgkmcnt(0)" ::: "memory");
  __builtin_amdgcn_s_barrier();
  __builtin_amdgcn_sched_barrier(0);

  // ---- 16 iterations; A banks rotate mod 3 ----
  ITER(0, bk1, bk0)  ITER(1, bk2, bk1)  ITER(2, bk0, bk2)  ITER(3, bk1, bk0)
  ITER(4, bk2, bk1)  ITER(5, bk0, bk2)  ITER(6, bk1, bk0)  ITER(7, bk2, bk1)
  ITER(8, bk0, bk2)  ITER(9, bk1, bk0)  ITER(10, bk2, bk1) ITER(11, bk0, bk2)
  ITER(12, bk1, bk0) ITER(13, bk2, bk1) ITER(14, bk0, bk2) ITER(15, bk1, bk0)

#undef ITER
#undef CSTEP
#undef B_STAGE
#undef A_WRITE
#undef A_LOAD

  asm volatile("s_waitcnt vmcnt(0)" ::: "memory");
  __syncthreads();

  // ---- epilogue: 8 phases of 16 rows (z[16][357] aliases smem front).
  // D layout: row = mf*16 + ablk*4 + reg, col = w*48 + nt*16 + arow.
#pragma unroll
  for (int p = 0; p < 8; p++) {
#pragma unroll
    for (int nt = 0; nt < 3; nt++) {
      if (!(w == 7 && nt >= 1)) {  // cols >= 352 are zero pad
#pragma unroll
        for (int r = 0; r < 4; r++)
          z[(ablk * 4 + r) * 357 + w * 48 + nt * 16 + arow] = acc[p][nt][r];
      }
    }
    __syncthreads();
    if (tid < 32) {
      const int t = tid >> 4, rr = tid & 15;
      const float* zr = &z[rr * 357];
      float gl[20], m = -1e30f;
#pragma unroll
      for (int u = 0; u < 20; u++) {
        gl[u] = zr[300 + t * 20 + u] + bias[300 + t * 20 + u];
        m = fmaxf(m, gl[u]);
      }
      float pr[20], s = 0.f;
#pragma unroll
      for (int u = 0; u < 20; u++) {
        pr[u] = __expf(gl[u] - m);
        s += pr[u];
      }
      const float inv = 1.f / s;
      const float* Wl = t ? Wv : Wc;
      float wl[10];
#pragma unroll
      for (int hh = 0; hh < 10; hh++) wl[hh] = Wl[hh];
      float accum = 0.f;
#pragma unroll
      for (int u = 0; u < 10; u++) {
        float d = 0.f;
#pragma unroll
        for (int hh = 0; hh < 10; hh++) {
          int c = t * 100 + u * 10 + hh;
          d += fmaxf(zr[c] + bias[c], 0.f) * wl[hh];
        }
        accum += pr[u] * d;
      }
#pragma unroll
      for (int u = 0; u < 10; u++) {
        float d = 0.f;
#pragma unroll
        for (int hh = 0; hh < 10; hh++) {
          int c = 200 + u * 10 + hh;
          d += fmaxf(zr[c] + bias[c], 0.f) * wl[hh];
        }
        accum += pr[10 + u] * d;
      }
      float logit = (t ? bv[0] : bc[0]) + accum * inv;
      out[(size_t)t * BROWS + rowbase + p * 16 + rr] =
          1.f / (1.f + __expf(-logit));
    }
    __syncthreads();
  }
}

extern "C" void kernel_launch(void* const* d_in, const int* in_sizes, int n_in,
                              void* d_out, int out_size, void* d_ws, size_t ws_size,
                              hipStream_t stream) {
  const float* x = (const float*)d_in[0];
  const float* Ws = (const float*)d_in[3];
  const float* bs = (const float*)d_in[4];
  const float* Wt = (const float*)d_in[5];
  const float* bt = (const float*)d_in[6];
  const float* Wg = (const float*)d_in[7];
  const float* bg = (const float*)d_in[8];
  const float* Wc = (const float*)d_in[9];
  const float* bc = (const float*)d_in[10];
  const float* Wv = (const float*)d_in[11];
  const float* bv = (const float*)d_in[12];
  unsigned short* Wpack = (unsigned short*)d_ws;
  float* bias = (float*)((char*)d_ws + (size_t)NCOLP * 1024 * 2);
  float* out = (float*)d_out;

  hipLaunchKernelGGL(ple_prep, dim3(NCOLP), dim3(256), 0, stream, Ws, bs, Wt, bt,
                     Wg, bg, Wpack, bias);
  hipLaunchKernelGGL(ple_main, dim3(BROWS / 128), dim3(512), 0, stream, x, Wpack,
                     bias, Wc, bc, Wv, bv, out);
}

// Round 22
// 86.040 us; speedup vs baseline: 2.5409x; 2.5409x over previous
//
#include <hip/hip_runtime.h>
#include <hip/hip_bf16.h>

typedef __attribute__((ext_vector_type(8))) short bf16x8;
typedef __attribute__((ext_vector_type(4))) float f32x4;

#define NCOLP 384                 // padded columns (352 real + 32 zero)
#define STEP_SHORTS (NCOLP * 32)  // 12288 shorts = 24576 B per 32-k step
#define STEP_BYTES 24576
#define SEG_BYTES 6144            // Wpack per-ablk segment: 384 cols * 8k * 2B
#define NSTEP 32
#define HSTEP 16
#define BROWS 65536

static __device__ __forceinline__ unsigned int bf16rne(float f) {
  unsigned int u = __float_as_uint(f);
  return (u + 0x7FFFu + ((u >> 16) & 1u)) >> 16;
}
static __device__ __forceinline__ unsigned int pack2(float a, float b) {
  return bf16rne(a) | (bf16rne(b) << 16);
}

// Wpack layout: [step][ablk(4)][col(384)][k%8] (bf16), 24576 B/step.
// Column map: [0,100) task0 (e*10+h), [100,200) task1, [200,300) shared,
// [300,340) gates (t*20+g), [340,384) zero pad.
__global__ void ple_prep(const float* __restrict__ Ws, const float* __restrict__ bs,
                         const float* __restrict__ Wt, const float* __restrict__ bt,
                         const float* __restrict__ Wg, const float* __restrict__ bg,
                         unsigned short* __restrict__ Wpack, float* __restrict__ bias) {
  const int n = blockIdx.x;  // 0..383
  const int tid = threadIdx.x;
  const float* src = nullptr;
  int stride = 0;
  float bval = 0.f;
  if (n < 200) {
    int t = n / 100, m = n % 100, e = m / 10, h = m % 10;
    src = Wt + (size_t)(t * 10 + e) * 10240 + h;
    stride = 10;
    bval = bt[(t * 10 + e) * 10 + h];
  } else if (n < 300) {
    int m = n - 200, e = m / 10, h = m % 10;
    src = Ws + (size_t)e * 10240 + h;
    stride = 10;
    bval = bs[e * 10 + h];
  } else if (n < 340) {
    int m = n - 300, t = m / 20, g = m % 20;
    src = Wg + (size_t)t * 20480 + g;
    stride = 20;
    bval = bg[t * 20 + g];
  }
  for (int j = 0; j < 4; j++) {
    int k = tid + j * 256;
    float v = src ? src[(size_t)k * stride] : 0.f;
    Wpack[(size_t)(k >> 5) * STEP_SHORTS + ((k >> 3) & 3) * (NCOLP * 8) + n * 8 +
          (k & 7)] = (unsigned short)bf16rne(v);
  }
  if (tid == 0 && n < 352) bias[n] = bval;
}

// Main: 256 threads = 4 waves, 64 rows/block, 1024 blocks, 2 blocks/CU.
// R19 phase-split structure + QUAD-BANKED B with lead-3 prefetch: step I
// consumes bank I%4 (loaded 3 steps earlier, ~720cy cover >= contended L2
// latency) and prefetches seq[I+3] into the just-retired bank. 3 banks
// preloaded before each stage phase (latency hides under stage-HBM).
// Anti-phase h0 block stagger retained.
__global__ __launch_bounds__(256, 2) void ple_main(
    const float* __restrict__ x, const unsigned short* __restrict__ Wpack,
    const float* __restrict__ bias, const float* __restrict__ Wc,
    const float* __restrict__ bc, const float* __restrict__ Wv,
    const float* __restrict__ bv, float* __restrict__ out) {
  // A half-tile: 64 rows x 64 segs(16B bf16, XOR-swizzled) = 65536 B.
  // Epilogue z[32][357] (45.7 KB) aliases it after the final barrier.
  __shared__ __align__(16) char smem[65536];
  float* z = (float*)smem;

  const int tid = threadIdx.x;
  const int l = tid & 63, w = tid >> 6;  // wave w -> cols [w*96, w*96+96)
  const int arow = l & 15, ablk = l >> 4;
  const int rowbase = blockIdx.x * 64;
  const int h0 = (int)(blockIdx.x & 1);  // first half processed (stagger)

  const f32x4 fzero = {0.f, 0.f, 0.f, 0.f};
  f32x4 acc[4][6];
#pragma unroll
  for (int i = 0; i < 4; ++i)
#pragma unroll
    for (int j = 0; j < 6; ++j) acc[i][j] = fzero;

  // B fragment base (per-lane 16B from Wpack; k-order matches A frags).
  const char* bbase = (const char*)Wpack + ablk * SEG_BYTES +
                      (w * 96 + arow) * 16;
  bf16x8 b0[6], b1[6], b2[6], b3[6];  // quad bank, static indexing only

  // Global step sequence: seq[i] = (h0*16 + i) & 31, i = 0..31.
  // Preload seq[0..2] -> b0..b2 (complete during the first stage phase).
#pragma unroll
  for (int nt = 0; nt < 6; nt++) {
    b0[nt] = *(const bf16x8*)(bbase + (size_t)(((h0 << 4) + 0) & 31) *
                                          STEP_BYTES + nt * 256);
    b1[nt] = *(const bf16x8*)(bbase + (size_t)(((h0 << 4) + 1) & 31) *
                                          STEP_BYTES + nt * 256);
    b2[nt] = *(const bf16x8*)(bbase + (size_t)(((h0 << 4) + 2) & 31) *
                                          STEP_BYTES + nt * 256);
  }

  // STEPX(I, BU, BP): consume bank BU (= seq[I]), prefetch seq[I+3] -> BP.
  // I compile-time; ksl = I & 15 indexes the LDS half-tile.
#define STEPX(I, BU, BP)                                                       \
  {                                                                            \
    const int ipre = ((I) + 3 <= 31) ? (I) + 3 : 31;                           \
    const int kpre = ((h0 << 4) + ipre) & 31;                                  \
    const char* bp = bbase + (size_t)kpre * STEP_BYTES;                        \
    _Pragma("unroll") for (int nt = 0; nt < 6; nt++)                           \
        BP[nt] = *(const bf16x8*)(bp + nt * 256);                              \
    _Pragma("unroll") for (int mf = 0; mf < 4; mf++) {                         \
      const int ksl = (I)&15;                                                  \
      const bf16x8 av = *(const bf16x8*)(smem + (mf * 16 + arow) * 1024 +      \
                                         (((ksl * 4 + ablk) ^ (arow & 7)) *    \
                                          16));                                \
      _Pragma("unroll") for (int nt = 0; nt < 6; nt++)                         \
          acc[mf][nt] = __builtin_amdgcn_mfma_f32_16x16x32_bf16(               \
              av, BU[nt], acc[mf][nt], 0, 0, 0);                               \
    }                                                                          \
  }

#pragma unroll
  for (int hh = 0; hh < 2; ++hh) {
    const int half = h0 ^ hh;
    // ---- stage phase: rows w + 4j (j=0..15); lane l = seg l (8 k) ----
    {
      const char* xb = (const char*)x + (size_t)(rowbase + w) * 4096 +
                       (size_t)half * 2048 + l * 32;
#pragma unroll 2
      for (int j = 0; j < 16; j++) {
        const float4 f0 = *(const float4*)(xb + (size_t)j * 4 * 4096);
        const float4 f1 = *(const float4*)(xb + (size_t)j * 4 * 4096 + 16);
        const int row = w + j * 4;
        char* dst = smem + row * 1024 + ((l ^ (row & 7)) * 16);
        *(uint4*)dst = make_uint4(pack2(f0.x, f0.y), pack2(f0.z, f0.w),
                                  pack2(f1.x, f1.y), pack2(f1.z, f1.w));
      }
    }
    __syncthreads();  // A half-tile visible to all waves

    // ---- compute phase: 16 K-steps, barrier-free, bank residue I%4 ----
    if (hh == 0) {
      STEPX(0, b0, b3)  STEPX(1, b1, b0)  STEPX(2, b2, b1)  STEPX(3, b3, b2)
      STEPX(4, b0, b3)  STEPX(5, b1, b0)  STEPX(6, b2, b1)  STEPX(7, b3, b2)
      STEPX(8, b0, b3)  STEPX(9, b1, b0)  STEPX(10, b2, b1) STEPX(11, b3, b2)
      STEPX(12, b0, b3) STEPX(13, b1, b0) STEPX(14, b2, b1) STEPX(15, b3, b2)
    } else {
      STEPX(16, b0, b3) STEPX(17, b1, b0) STEPX(18, b2, b1) STEPX(19, b3, b2)
      STEPX(20, b0, b3) STEPX(21, b1, b0) STEPX(22, b2, b1) STEPX(23, b3, b2)
      STEPX(24, b0, b3) STEPX(25, b1, b0) STEPX(26, b2, b1) STEPX(27, b3, b2)
      STEPX(28, b0, b3) STEPX(29, b1, b0) STEPX(30, b2, b1) STEPX(31, b3, b2)
    }
    __syncthreads();  // all reads done before next stage / epilogue reuse
  }
#undef STEPX

  // ---- epilogue: 2 phases of 32 rows. D layout: row=(l>>4)*4+reg, col=l&15.
#pragma unroll
  for (int p = 0; p < 2; p++) {
    __syncthreads();
#pragma unroll
    for (int q = 0; q < 2; q++) {
      const int mf = p * 2 + q;
#pragma unroll
      for (int nt = 0; nt < 6; nt++) {
        if (w == 3 && nt >= 4) continue;  // cols >= 352 are zero pad
#pragma unroll
        for (int r = 0; r < 4; r++)
          z[(q * 16 + ablk * 4 + r) * 357 + w * 96 + nt * 16 + arow] =
              acc[mf][nt][r];
      }
    }
    __syncthreads();
    if (tid < 64) {
      const int t = tid >> 5, r = tid & 31;
      const float* zr = &z[r * 357];
      float gl[20], m = -1e30f;
#pragma unroll
      for (int u = 0; u < 20; u++) {
        gl[u] = zr[300 + t * 20 + u] + bias[300 + t * 20 + u];
        m = fmaxf(m, gl[u]);
      }
      float pr[20], s = 0.f;
#pragma unroll
      for (int u = 0; u < 20; u++) {
        pr[u] = __expf(gl[u] - m);
        s += pr[u];
      }
      const float inv = 1.f / s;
      const float* Wl = t ? Wv : Wc;
      float wl[10];
#pragma unroll
      for (int h = 0; h < 10; h++) wl[h] = Wl[h];
      float accum = 0.f;
#pragma unroll
      for (int u = 0; u < 10; u++) {
        float d = 0.f;
#pragma unroll
        for (int h = 0; h < 10; h++) {
          int c = t * 100 + u * 10 + h;
          d += fmaxf(zr[c] + bias[c], 0.f) * wl[h];
        }
        accum += pr[u] * d;
      }
#pragma unroll
      for (int u = 0; u < 10; u++) {
        float d = 0.f;
#pragma unroll
        for (int h = 0; h < 10; h++) {
          int c = 200 + u * 10 + h;
          d += fmaxf(zr[c] + bias[c], 0.f) * wl[h];
        }
        accum += pr[10 + u] * d;
      }
      float logit = (t ? bv[0] : bc[0]) + accum * inv;
      out[(size_t)t * BROWS + rowbase + p * 32 + r] =
          1.f / (1.f + __expf(-logit));
    }
  }
}

extern "C" void kernel_launch(void* const* d_in, const int* in_sizes, int n_in,
                              void* d_out, int out_size, void* d_ws, size_t ws_size,
                              hipStream_t stream) {
  const float* x = (const float*)d_in[0];
  const float* Ws = (const float*)d_in[3];
  const float* bs = (const float*)d_in[4];
  const float* Wt = (const float*)d_in[5];
  const float* bt = (const float*)d_in[6];
  const float* Wg = (const float*)d_in[7];
  const float* bg = (const float*)d_in[8];
  const float* Wc = (const float*)d_in[9];
  const float* bc = (const float*)d_in[10];
  const float* Wv = (const float*)d_in[11];
  const float* bv = (const float*)d_in[12];
  unsigned short* Wpack = (unsigned short*)d_ws;
  float* bias = (float*)((char*)d_ws + (size_t)NCOLP * 1024 * 2);
  float* out = (float*)d_out;

  hipLaunchKernelGGL(ple_prep, dim3(NCOLP), dim3(256), 0, stream, Ws, bs, Wt, bt,
                     Wg, bg, Wpack, bias);
  hipLaunchKernelGGL(ple_main, dim3(BROWS / 64), dim3(256), 0, stream, x, Wpack,
                     bias, Wc, bc, Wv, bv, out);
}

// Round 23
// 81.297 us; speedup vs baseline: 2.6892x; 1.0583x over previous
//
#include <hip/hip_runtime.h>
#include <hip/hip_bf16.h>

typedef __attribute__((ext_vector_type(8))) short bf16x8;
typedef __attribute__((ext_vector_type(4))) float f32x4;

#define NCOLP 384                 // padded columns (352 real + 32 zero)
#define STEP_SHORTS (NCOLP * 32)  // 12288 shorts = 24576 B per 32-k step
#define STEP_BYTES 24576
#define SEG_BYTES 6144            // Wpack per-ablk segment: 384 cols * 8k * 2B
#define NSTEP 32
#define HSTEP 16
#define BROWS 65536

static __device__ __forceinline__ unsigned int bf16rne(float f) {
  unsigned int u = __float_as_uint(f);
  return (u + 0x7FFFu + ((u >> 16) & 1u)) >> 16;
}
static __device__ __forceinline__ unsigned int pack2(float a, float b) {
  return bf16rne(a) | (bf16rne(b) << 16);
}

// Wpack layout: [step][ablk(4)][col(384)][k%8] (bf16), 24576 B/step.
// Column map: [0,100) task0 (e*10+h), [100,200) task1, [200,300) shared,
// [300,340) gates (t*20+g), [340,384) zero pad.
__global__ void ple_prep(const float* __restrict__ Ws, const float* __restrict__ bs,
                         const float* __restrict__ Wt, const float* __restrict__ bt,
                         const float* __restrict__ Wg, const float* __restrict__ bg,
                         unsigned short* __restrict__ Wpack, float* __restrict__ bias) {
  const int n = blockIdx.x;  // 0..383
  const int tid = threadIdx.x;
  const float* src = nullptr;
  int stride = 0;
  float bval = 0.f;
  if (n < 200) {
    int t = n / 100, m = n % 100, e = m / 10, h = m % 10;
    src = Wt + (size_t)(t * 10 + e) * 10240 + h;
    stride = 10;
    bval = bt[(t * 10 + e) * 10 + h];
  } else if (n < 300) {
    int m = n - 200, e = m / 10, h = m % 10;
    src = Ws + (size_t)e * 10240 + h;
    stride = 10;
    bval = bs[e * 10 + h];
  } else if (n < 340) {
    int m = n - 300, t = m / 20, g = m % 20;
    src = Wg + (size_t)t * 20480 + g;
    stride = 20;
    bval = bg[t * 20 + g];
  }
  for (int j = 0; j < 4; j++) {
    int k = tid + j * 256;
    float v = src ? src[(size_t)k * stride] : 0.f;
    Wpack[(size_t)(k >> 5) * STEP_SHORTS + ((k >> 3) & 3) * (NCOLP * 8) + n * 8 +
          (k & 7)] = (unsigned short)bf16rne(v);
  }
  if (tid == 0 && n < 352) bias[n] = bval;
}

// Main: 256 threads = 4 waves, 64 rows/block, 1024 blocks, 2 blocks/CU.
// R19 (champion) + (a) depth-6 grouped stage: {12 loads -> 6 writes} x2 +
// {8 -> 4}: 3 HBM-latency stalls per half-stage instead of 4; (b)
// 4-way-parallel epilogue: 4 threads per (task,row) item, 5 experts each,
// __shfl_xor reduce -> all 256 threads busy. Triple-banked lead-2 B and
// anti-phase h0 stagger retained.
__global__ __launch_bounds__(256, 2) void ple_main(
    const float* __restrict__ x, const unsigned short* __restrict__ Wpack,
    const float* __restrict__ bias, const float* __restrict__ Wc,
    const float* __restrict__ bc, const float* __restrict__ Wv,
    const float* __restrict__ bv, float* __restrict__ out) {
  // A half-tile: 64 rows x 64 segs(16B bf16, XOR-swizzled) = 65536 B.
  // Epilogue z[32][357] (45.7 KB) aliases it after the final barrier.
  __shared__ __align__(16) char smem[65536];
  float* z = (float*)smem;

  const int tid = threadIdx.x;
  const int l = tid & 63, w = tid >> 6;  // wave w -> cols [w*96, w*96+96)
  const int arow = l & 15, ablk = l >> 4;
  const int rowbase = blockIdx.x * 64;
  const int h0 = (int)(blockIdx.x & 1);  // first half processed (stagger)

  const f32x4 fzero = {0.f, 0.f, 0.f, 0.f};
  f32x4 acc[4][6];
#pragma unroll
  for (int i = 0; i < 4; ++i)
#pragma unroll
    for (int j = 0; j < 6; ++j) acc[i][j] = fzero;

  // B fragment base (per-lane 16B from Wpack; k-order matches A frags).
  const char* bbase = (const char*)Wpack + ablk * SEG_BYTES +
                      (w * 96 + arow) * 16;
  bf16x8 b0[6], b1[6], b2[6];  // triple bank, static indexing only

  // Global step sequence: seq[i] = (h0*16 + i) & 31. Preload seq[0..1].
#pragma unroll
  for (int nt = 0; nt < 6; nt++) {
    b0[nt] = *(const bf16x8*)(bbase + (size_t)(((h0 << 4) + 0) & 31) *
                                          STEP_BYTES + nt * 256);
    b1[nt] = *(const bf16x8*)(bbase + (size_t)(((h0 << 4) + 1) & 31) *
                                          STEP_BYTES + nt * 256);
  }

  // STEPX(I, BU, BP): consume bank BU (= seq[I]), prefetch seq[I+2] -> BP.
#define STEPX(I, BU, BP)                                                       \
  {                                                                            \
    const int ipre = ((I) + 2 <= 31) ? (I) + 2 : 31;                           \
    const int kpre = ((h0 << 4) + ipre) & 31;                                  \
    const char* bp = bbase + (size_t)kpre * STEP_BYTES;                        \
    _Pragma("unroll") for (int nt = 0; nt < 6; nt++)                           \
        BP[nt] = *(const bf16x8*)(bp + nt * 256);                              \
    _Pragma("unroll") for (int mf = 0; mf < 4; mf++) {                         \
      const int ksl = (I)&15;                                                  \
      const bf16x8 av = *(const bf16x8*)(smem + (mf * 16 + arow) * 1024 +      \
                                         (((ksl * 4 + ablk) ^ (arow & 7)) *    \
                                          16));                                \
      _Pragma("unroll") for (int nt = 0; nt < 6; nt++)                         \
          acc[mf][nt] = __builtin_amdgcn_mfma_f32_16x16x32_bf16(               \
              av, BU[nt], acc[mf][nt], 0, 0, 0);                               \
    }                                                                          \
  }

  // Stage helpers: row w + 4j, lane l = seg l (8 k = 32B fp32).
#define SLOAD(J, FA, FB)                                                       \
  const float4 FA = *(const float4*)(xb + (size_t)(J) * 4 * 4096);             \
  const float4 FB = *(const float4*)(xb + (size_t)(J) * 4 * 4096 + 16);
#define SWRITE(J, FA, FB)                                                      \
  {                                                                            \
    const int row = w + (J)*4;                                                 \
    char* dst = smem + row * 1024 + ((l ^ (row & 7)) * 16);                    \
    *(uint4*)dst = make_uint4(pack2(FA.x, FA.y), pack2(FA.z, FA.w),            \
                              pack2(FB.x, FB.y), pack2(FB.z, FB.w));           \
  }

#pragma unroll
  for (int hh = 0; hh < 2; ++hh) {
    const int half = h0 ^ hh;
    // ---- stage phase: depth-6 groups (12 loads then 6 writes) ----
    {
      const char* xb = (const char*)x + (size_t)(rowbase + w) * 4096 +
                       (size_t)half * 2048 + l * 32;
      {
        SLOAD(0, a0, c0) SLOAD(1, a1, c1) SLOAD(2, a2, c2)
        SLOAD(3, a3, c3) SLOAD(4, a4, c4) SLOAD(5, a5, c5)
        SWRITE(0, a0, c0) SWRITE(1, a1, c1) SWRITE(2, a2, c2)
        SWRITE(3, a3, c3) SWRITE(4, a4, c4) SWRITE(5, a5, c5)
      }
      {
        SLOAD(6, a0, c0) SLOAD(7, a1, c1) SLOAD(8, a2, c2)
        SLOAD(9, a3, c3) SLOAD(10, a4, c4) SLOAD(11, a5, c5)
        SWRITE(6, a0, c0) SWRITE(7, a1, c1) SWRITE(8, a2, c2)
        SWRITE(9, a3, c3) SWRITE(10, a4, c4) SWRITE(11, a5, c5)
      }
      {
        SLOAD(12, a0, c0) SLOAD(13, a1, c1) SLOAD(14, a2, c2)
        SLOAD(15, a3, c3)
        SWRITE(12, a0, c0) SWRITE(13, a1, c1) SWRITE(14, a2, c2)
        SWRITE(15, a3, c3)
      }
    }
    __syncthreads();  // A half-tile visible to all waves

    // ---- compute phase: 16 K-steps, barrier-free, bank residue I%3 ----
    if (hh == 0) {
      STEPX(0, b0, b2)  STEPX(1, b1, b0)  STEPX(2, b2, b1)
      STEPX(3, b0, b2)  STEPX(4, b1, b0)  STEPX(5, b2, b1)
      STEPX(6, b0, b2)  STEPX(7, b1, b0)  STEPX(8, b2, b1)
      STEPX(9, b0, b2)  STEPX(10, b1, b0) STEPX(11, b2, b1)
      STEPX(12, b0, b2) STEPX(13, b1, b0) STEPX(14, b2, b1)
      STEPX(15, b0, b2)
    } else {
      STEPX(16, b1, b0) STEPX(17, b2, b1) STEPX(18, b0, b2)
      STEPX(19, b1, b0) STEPX(20, b2, b1) STEPX(21, b0, b2)
      STEPX(22, b1, b0) STEPX(23, b2, b1) STEPX(24, b0, b2)
      STEPX(25, b1, b0) STEPX(26, b2, b1) STEPX(27, b0, b2)
      STEPX(28, b1, b0) STEPX(29, b2, b1) STEPX(30, b0, b2)
      STEPX(31, b1, b0)
    }
    __syncthreads();  // all reads done before next stage / epilogue reuse
  }
#undef STEPX
#undef SLOAD
#undef SWRITE

  // ---- epilogue: 2 phases of 32 rows; 4 threads per (task,row) item.
  // D layout: row=(l>>4)*4+reg, col=l&15.
#pragma unroll
  for (int p = 0; p < 2; p++) {
    __syncthreads();
#pragma unroll
    for (int q = 0; q < 2; q++) {
      const int mf = p * 2 + q;
#pragma unroll
      for (int nt = 0; nt < 6; nt++) {
        if (w == 3 && nt >= 4) continue;  // cols >= 352 are zero pad
#pragma unroll
        for (int r = 0; r < 4; r++)
          z[(q * 16 + ablk * 4 + r) * 357 + w * 96 + nt * 16 + arow] =
              acc[mf][nt][r];
      }
    }
    __syncthreads();
    {
      const int item = tid >> 2, sub = tid & 3;  // 64 items x 4 threads
      const int t = item >> 5, r = item & 31;
      const float* zr = &z[r * 357];
      // local 5 gates: u = sub*5 + v
      float gl[5], m = -1e30f;
#pragma unroll
      for (int v = 0; v < 5; v++) {
        const int u = sub * 5 + v;
        gl[v] = zr[300 + t * 20 + u] + bias[300 + t * 20 + u];
        m = fmaxf(m, gl[v]);
      }
      m = fmaxf(m, __shfl_xor(m, 1));
      m = fmaxf(m, __shfl_xor(m, 2));
      const float* Wl = t ? Wv : Wc;
      float wl[10];
#pragma unroll
      for (int h = 0; h < 10; h++) wl[h] = Wl[h];
      float s = 0.f, accum = 0.f;
#pragma unroll
      for (int v = 0; v < 5; v++) {
        const int u = sub * 5 + v;
        const float pu = __expf(gl[v] - m);
        s += pu;
        const int cbase = (u < 10) ? (t * 100 + u * 10) : (200 + (u - 10) * 10);
        float d = 0.f;
#pragma unroll
        for (int h = 0; h < 10; h++)
          d += fmaxf(zr[cbase + h] + bias[cbase + h], 0.f) * wl[h];
        accum += pu * d;
      }
      s += __shfl_xor(s, 1);
      s += __shfl_xor(s, 2);
      accum += __shfl_xor(accum, 1);
      accum += __shfl_xor(accum, 2);
      if (sub == 0) {
        const float logit = (t ? bv[0] : bc[0]) + accum / s;
        out[(size_t)t * BROWS + rowbase + p * 32 + r] =
            1.f / (1.f + __expf(-logit));
      }
    }
  }
}

extern "C" void kernel_launch(void* const* d_in, const int* in_sizes, int n_in,
                              void* d_out, int out_size, void* d_ws, size_t ws_size,
                              hipStream_t stream) {
  const float* x = (const float*)d_in[0];
  const float* Ws = (const float*)d_in[3];
  const float* bs = (const float*)d_in[4];
  const float* Wt = (const float*)d_in[5];
  const float* bt = (const float*)d_in[6];
  const float* Wg = (const float*)d_in[7];
  const float* bg = (const float*)d_in[8];
  const float* Wc = (const float*)d_in[9];
  const float* bc = (const float*)d_in[10];
  const float* Wv = (const float*)d_in[11];
  const float* bv = (const float*)d_in[12];
  unsigned short* Wpack = (unsigned short*)d_ws;
  float* bias = (float*)((char*)d_ws + (size_t)NCOLP * 1024 * 2);
  float* out = (float*)d_out;

  hipLaunchKernelGGL(ple_prep, dim3(NCOLP), dim3(256), 0, stream, Ws, bs, Wt, bt,
                     Wg, bg, Wpack, bias);
  hipLaunchKernelGGL(ple_main, dim3(BROWS / 64), dim3(256), 0, stream, x, Wpack,
                     bias, Wc, bc, Wv, bv, out);
}

// Round 24
// 79.763 us; speedup vs baseline: 2.7409x; 1.0192x over previous
//
#include <hip/hip_runtime.h>
#include <hip/hip_bf16.h>

typedef __attribute__((ext_vector_type(8))) short bf16x8;
typedef __attribute__((ext_vector_type(4))) float f32x4;

#define NCOLP 384                 // padded columns (352 real + 32 zero)
#define STEP_SHORTS (NCOLP * 32)  // 12288 shorts = 24576 B per 32-k step
#define STEP_BYTES 24576
#define SEG_BYTES 6144            // Wpack per-ablk segment: 384 cols * 8k * 2B
#define NSTEP 32
#define BROWS 65536
#define QSZ 32768                 // quarter tile: 64 rows x 512 B bf16

static __device__ __forceinline__ unsigned int bf16rne(float f) {
  unsigned int u = __float_as_uint(f);
  return (u + 0x7FFFu + ((u >> 16) & 1u)) >> 16;
}
static __device__ __forceinline__ unsigned int pack2(float a, float b) {
  return bf16rne(a) | (bf16rne(b) << 16);
}

// Wpack layout: [step][ablk(4)][col(384)][k%8] (bf16), 24576 B/step.
// Column map: [0,100) task0 (e*10+h), [100,200) task1, [200,300) shared,
// [300,340) gates (t*20+g), [340,384) zero pad.
__global__ void ple_prep(const float* __restrict__ Ws, const float* __restrict__ bs,
                         const float* __restrict__ Wt, const float* __restrict__ bt,
                         const float* __restrict__ Wg, const float* __restrict__ bg,
                         unsigned short* __restrict__ Wpack, float* __restrict__ bias) {
  const int n = blockIdx.x;  // 0..383
  const int tid = threadIdx.x;
  const float* src = nullptr;
  int stride = 0;
  float bval = 0.f;
  if (n < 200) {
    int t = n / 100, m = n % 100, e = m / 10, h = m % 10;
    src = Wt + (size_t)(t * 10 + e) * 10240 + h;
    stride = 10;
    bval = bt[(t * 10 + e) * 10 + h];
  } else if (n < 300) {
    int m = n - 200, e = m / 10, h = m % 10;
    src = Ws + (size_t)e * 10240 + h;
    stride = 10;
    bval = bs[e * 10 + h];
  } else if (n < 340) {
    int m = n - 300, t = m / 20, g = m % 20;
    src = Wg + (size_t)t * 20480 + g;
    stride = 20;
    bval = bg[t * 20 + g];
  }
  for (int j = 0; j < 4; j++) {
    int k = tid + j * 256;
    float v = src ? src[(size_t)k * stride] : 0.f;
    Wpack[(size_t)(k >> 5) * STEP_SHORTS + ((k >> 3) & 3) * (NCOLP * 8) + n * 8 +
          (k & 7)] = (unsigned short)bf16rne(v);
  }
  if (tid == 0 && n < 352) bias[n] = bval;
}

// Main: 256 threads = 4 waves, 64 rows/block, 1024 blocks, 2 blocks/CU.
// DOUBLE-BUFFERED QUARTER TILES WITH IN-COMPUTE STAGING: per quarter
// (8 K-steps from buf[q&1], triple-banked lead-2 register B), the next
// quarter's 16 A-loads are issued in two groups of 8 DURING compute
// (after steps 1 and 4) and packed+ds_written (after steps 4 and 7) into
// buf[(q+1)&1]; one lgkm-only barrier per quarter. FIFO-traced: B-consume
// waits never force the younger A-groups; A-pack waits give each group
// ~700cy of HBM cover. HBM stays busy under compute -> stage leaves the
// critical path. Regs ~230 on the proven 256-thr/(256,2) chassis.
__global__ __launch_bounds__(256, 2) void ple_main(
    const float* __restrict__ x, const unsigned short* __restrict__ Wpack,
    const float* __restrict__ bias, const float* __restrict__ Wc,
    const float* __restrict__ bc, const float* __restrict__ Wv,
    const float* __restrict__ bv, float* __restrict__ out) {
  __shared__ __align__(16) char smem[2 * QSZ];  // z[32][357] aliases front
  float* z = (float*)smem;

  const int tid = threadIdx.x;
  const int l = tid & 63, w = tid >> 6;  // wave w -> cols [w*96, w*96+96)
  const int arow = l & 15, ablk = l >> 4;
  const int rowbase = blockIdx.x * 64;

  const f32x4 fzero = {0.f, 0.f, 0.f, 0.f};
  f32x4 acc[4][6];
#pragma unroll
  for (int i = 0; i < 4; ++i)
#pragma unroll
    for (int j = 0; j < 6; ++j) acc[i][j] = fzero;

  // B fragment base (per-lane 16B from Wpack; k-order matches A frags).
  const char* bbase = (const char*)Wpack + ablk * SEG_BYTES +
                      (w * 96 + arow) * 16;
  bf16x8 b0[6], b1[6], b2[6];  // triple bank, static indexing only

  // Preload B steps 0,1.
#pragma unroll
  for (int nt = 0; nt < 6; nt++) {
    b0[nt] = *(const bf16x8*)(bbase + nt * 256);
    b1[nt] = *(const bf16x8*)(bbase + STEP_BYTES + nt * 256);
  }

  // A staging: wave w covers rows w+4j (j=0..15); lane l = 16B fp32 seg l
  // of the current quarter (64 lanes x 16B = 1KB/row/quarter, coalesced).
  const char* xstage = (const char*)x + (size_t)(rowbase + w) * 4096 + l * 16;
  float4 g[8], hgrp[8];

#define GISSUE(Q, G, J0)                                                       \
  {                                                                            \
    _Pragma("unroll") for (int j = 0; j < 8; j++)                              \
        G[j] = *(const float4*)(xstage + (size_t)((J0) + j) * 4 * 4096 +       \
                                (Q)*1024);                                     \
  }
#define GWRITE(Q, G, J0)                                                       \
  {                                                                            \
    _Pragma("unroll") for (int j = 0; j < 8; j++) {                            \
      const int row = w + ((J0) + j) * 4;                                      \
      const int s = l >> 1;                                                    \
      const int segp = (s & 24) | ((s & 7) ^ (row & 7));                       \
      uint2 u;                                                                 \
      u.x = pack2(G[j].x, G[j].y);                                             \
      u.y = pack2(G[j].z, G[j].w);                                             \
      *(uint2*)(smem + ((Q)&1) * QSZ + row * 512 + segp * 16 + (l & 1) * 8) =  \
          u;                                                                   \
    }                                                                          \
  }
  // STEPX(I, BU, BP): consume bank BU (= step I), prefetch step I+2 -> BP.
  // Reads A from buf[(I>>3)&1], quarter-local seg s = (I&7)*4+ablk.
#define STEPX(I, BU, BP)                                                       \
  {                                                                            \
    const int ipre = ((I) + 2 <= 31) ? (I) + 2 : 31;                           \
    const char* bp = bbase + (size_t)ipre * STEP_BYTES;                        \
    _Pragma("unroll") for (int nt = 0; nt < 6; nt++)                           \
        BP[nt] = *(const bf16x8*)(bp + nt * 256);                              \
    _Pragma("unroll") for (int mf = 0; mf < 4; mf++) {                         \
      const int s = ((I)&7) * 4 + ablk;                                        \
      const int segp = (s & 24) | ((s & 7) ^ (arow & 7));                      \
      const bf16x8 av =                                                        \
          *(const bf16x8*)(smem + (((I) >> 3) & 1) * QSZ +                     \
                           (mf * 16 + arow) * 512 + segp * 16);                \
      _Pragma("unroll") for (int nt = 0; nt < 6; nt++)                         \
          acc[mf][nt] = __builtin_amdgcn_mfma_f32_16x16x32_bf16(               \
              av, BU[nt], acc[mf][nt], 0, 0, 0);                               \
    }                                                                          \
  }
#define SB __builtin_amdgcn_sched_barrier(0);
#define QBAR                                                                   \
  asm volatile("s_waitcnt lgkmcnt(0)" ::: "memory");                           \
  __builtin_amdgcn_s_barrier();

  // ---- prologue: stage quarter 0 -> buf0 (depth-8 groups) ----
  GISSUE(0, g, 0) SB GWRITE(0, g, 0) SB GISSUE(0, hgrp, 8) SB
  GWRITE(0, hgrp, 8) QBAR SB

  // ---- Q0: compute buf0 (steps 0-7), stage quarter1 -> buf1 ----
  STEPX(0, b0, b2) STEPX(1, b1, b0)
  SB GISSUE(1, g, 0) SB
  STEPX(2, b2, b1) STEPX(3, b0, b2) STEPX(4, b1, b0)
  SB GWRITE(1, g, 0) SB GISSUE(1, hgrp, 8) SB
  STEPX(5, b2, b1) STEPX(6, b0, b2) STEPX(7, b1, b0)
  SB GWRITE(1, hgrp, 8) QBAR SB

  // ---- Q1: compute buf1 (steps 8-15), stage quarter2 -> buf0 ----
  STEPX(8, b2, b1) STEPX(9, b0, b2)
  SB GISSUE(2, g, 0) SB
  STEPX(10, b1, b0) STEPX(11, b2, b1) STEPX(12, b0, b2)
  SB GWRITE(2, g, 0) SB GISSUE(2, hgrp, 8) SB
  STEPX(13, b1, b0) STEPX(14, b2, b1) STEPX(15, b0, b2)
  SB GWRITE(2, hgrp, 8) QBAR SB

  // ---- Q2: compute buf0 (steps 16-23), stage quarter3 -> buf1 ----
  STEPX(16, b1, b0) STEPX(17, b2, b1)
  SB GISSUE(3, g, 0) SB
  STEPX(18, b0, b2) STEPX(19, b1, b0) STEPX(20, b2, b1)
  SB GWRITE(3, g, 0) SB GISSUE(3, hgrp, 8) SB
  STEPX(21, b0, b2) STEPX(22, b1, b0) STEPX(23, b2, b1)
  SB GWRITE(3, hgrp, 8) QBAR SB

  // ---- Q3: compute buf1 (steps 24-31), no staging ----
  STEPX(24, b0, b2) STEPX(25, b1, b0) STEPX(26, b2, b1) STEPX(27, b0, b2)
  STEPX(28, b1, b0) STEPX(29, b2, b1) STEPX(30, b0, b2) STEPX(31, b1, b0)
  QBAR

#undef QBAR
#undef SB
#undef STEPX
#undef GWRITE
#undef GISSUE

  // ---- epilogue: 2 phases of 32 rows; 4 threads per (task,row) item.
  // D layout: row=(l>>4)*4+reg, col=l&15.
#pragma unroll
  for (int p = 0; p < 2; p++) {
    __syncthreads();
#pragma unroll
    for (int q = 0; q < 2; q++) {
      const int mf = p * 2 + q;
#pragma unroll
      for (int nt = 0; nt < 6; nt++) {
        if (w == 3 && nt >= 4) continue;  // cols >= 352 are zero pad
#pragma unroll
        for (int r = 0; r < 4; r++)
          z[(q * 16 + ablk * 4 + r) * 357 + w * 96 + nt * 16 + arow] =
              acc[mf][nt][r];
      }
    }
    __syncthreads();
    {
      const int item = tid >> 2, sub = tid & 3;  // 64 items x 4 threads
      const int t = item >> 5, r = item & 31;
      const float* zr = &z[r * 357];
      float gl[5], m = -1e30f;
#pragma unroll
      for (int v = 0; v < 5; v++) {
        const int u = sub * 5 + v;
        gl[v] = zr[300 + t * 20 + u] + bias[300 + t * 20 + u];
        m = fmaxf(m, gl[v]);
      }
      m = fmaxf(m, __shfl_xor(m, 1));
      m = fmaxf(m, __shfl_xor(m, 2));
      const float* Wl = t ? Wv : Wc;
      float wl[10];
#pragma unroll
      for (int h = 0; h < 10; h++) wl[h] = Wl[h];
      float s = 0.f, accum = 0.f;
#pragma unroll
      for (int v = 0; v < 5; v++) {
        const int u = sub * 5 + v;
        const float pu = __expf(gl[v] - m);
        s += pu;
        const int cbase = (u < 10) ? (t * 100 + u * 10) : (200 + (u - 10) * 10);
        float d = 0.f;
#pragma unroll
        for (int h = 0; h < 10; h++)
          d += fmaxf(zr[cbase + h] + bias[cbase + h], 0.f) * wl[h];
        accum += pu * d;
      }
      s += __shfl_xor(s, 1);
      s += __shfl_xor(s, 2);
      accum += __shfl_xor(accum, 1);
      accum += __shfl_xor(accum, 2);
      if (sub == 0) {
        const float logit = (t ? bv[0] : bc[0]) + accum / s;
        out[(size_t)t * BROWS + rowbase + p * 32 + r] =
            1.f / (1.f + __expf(-logit));
      }
    }
  }
}

extern "C" void kernel_launch(void* const* d_in, const int* in_sizes, int n_in,
                              void* d_out, int out_size, void* d_ws, size_t ws_size,
                              hipStream_t stream) {
  const float* x = (const float*)d_in[0];
  const float* Ws = (const float*)d_in[3];
  const float* bs = (const float*)d_in[4];
  const float* Wt = (const float*)d_in[5];
  const float* bt = (const float*)d_in[6];
  const float* Wg = (const float*)d_in[7];
  const float* bg = (const float*)d_in[8];
  const float* Wc = (const float*)d_in[9];
  const float* bc = (const float*)d_in[10];
  const float* Wv = (const float*)d_in[11];
  const float* bv = (const float*)d_in[12];
  unsigned short* Wpack = (unsigned short*)d_ws;
  float* bias = (float*)((char*)d_ws + (size_t)NCOLP * 1024 * 2);
  float* out = (float*)d_out;

  hipLaunchKernelGGL(ple_prep, dim3(NCOLP), dim3(256), 0, stream, Ws, bs, Wt, bt,
                     Wg, bg, Wpack, bias);
  hipLaunchKernelGGL(ple_main, dim3(BROWS / 64), dim3(256), 0, stream, x, Wpack,
                     bias, Wc, bc, Wv, bv, out);
}